// Round 13
// baseline (2995.449 us; speedup 1.0000x reference)
//
#include <hip/hip_runtime.h>
#include <hip/hip_bf16.h>

typedef short bf16x8 __attribute__((ext_vector_type(8)));
typedef float f32x4 __attribute__((ext_vector_type(4)));
using bf16 = __hip_bfloat16;

#define GLOBAL_LOAD_LDS16(g, l)                                                          \
    __builtin_amdgcn_global_load_lds((const __attribute__((address_space(1))) unsigned int*)(g), \
                                     (__attribute__((address_space(3))) unsigned int*)(l), \
                                     16, 0, 0)

// ---------------------------------------------------------------- utilities
static __device__ __forceinline__ float gelu_f(float x) {
    float u = 1.5957691216057308f * x * (1.0f + 0.044715f * x * x);
    return x / (1.0f + __expf(-u));
}

static __device__ __forceinline__ unsigned pack_bf16(float lo, float hi) {
    union { bf16 h; unsigned short u; } a, b;
    a.h = __float2bfloat16(lo);
    b.h = __float2bfloat16(hi);
    return ((unsigned)b.u << 16) | (unsigned)a.u;
}

// ---------------------------------------------------------------- transpose + downcast (f32 -> bf16), batched over z
__global__ __launch_bounds__(256) void transpose_f32_bf16(const float* __restrict__ in,
                                                          bf16* __restrict__ out,
                                                          int R, int C, size_t zso) {
    __shared__ float tile[32][33];
    size_t zi = (size_t)blockIdx.z * R * C;
    size_t zo = (size_t)blockIdx.z * zso;
    int c0 = blockIdx.x * 32, r0 = blockIdx.y * 32;
    int tx = threadIdx.x & 31, ty = threadIdx.x >> 5;
    #pragma unroll
    for (int i = 0; i < 32; i += 8) {
        int r = r0 + ty + i, c = c0 + tx;
        if (r < R && c < C) tile[ty + i][tx] = in[zi + (size_t)r * C + c];
    }
    __syncthreads();
    #pragma unroll
    for (int i = 0; i < 32; i += 8) {
        int c = c0 + ty + i, r = r0 + tx;
        if (c < C && r < R) out[zo + (size_t)c * R + r] = __float2bfloat16(tile[tx][ty + i]);
    }
}

// ---------------------------------------------------------------- bias concat: [L][1536] = bq|bk|bv
__global__ __launch_bounds__(256) void concat_bias(const float* __restrict__ bq,
                                                   const float* __restrict__ bk,
                                                   const float* __restrict__ bv,
                                                   float* __restrict__ out) {
    int i = blockIdx.x * 256 + threadIdx.x;
    if (i < 3 * 1536) {
        int L = i / 1536, r = i - L * 1536;
        float v = (r < 512) ? bq[L * 512 + r]
                : (r < 1024) ? bk[L * 512 + r - 512]
                             : bv[L * 512 + r - 1024];
        out[i] = v;
    }
}

// ---------------------------------------------------------------- V transpose: qkv[b*240+t][1536] (cols 1024..1535) -> vt[b*512+d][240]
__global__ __launch_bounds__(256) void transpose_v(const bf16* __restrict__ in,
                                                   bf16* __restrict__ out) {
    __shared__ bf16 tile[32][33];
    int b = blockIdx.z;
    int d0 = blockIdx.x * 32, t0 = blockIdx.y * 32;
    int tx = threadIdx.x & 31, ty = threadIdx.x >> 5;
    #pragma unroll
    for (int i = 0; i < 32; i += 8) {
        int tt = t0 + ty + i, dd = d0 + tx;
        if (tt < 240) tile[ty + i][tx] = in[((size_t)b * 240 + tt) * 1536 + 1024 + dd];
    }
    __syncthreads();
    #pragma unroll
    for (int i = 0; i < 32; i += 8) {
        int dd = d0 + ty + i, tt = t0 + tx;
        if (tt < 240) out[((size_t)b * 512 + dd) * 240 + tt] = tile[tx][ty + i];
    }
}

// ---------------------------------------------------------------- patch embedding + positional encoding
__global__ __launch_bounds__(256) void embed_kernel(const float* __restrict__ x_enc,
                                                    const float* __restrict__ W_emb, // [16][512]
                                                    bf16* __restrict__ h) {
    int row = blockIdx.x;
    int b = row / 240, l = row - b * 240;
    int s = (l < 16) ? 0 : (l < 48) ? 1 : (l < 112) ? 2 : 3;
    int len = 16 << s;
    int off = len - 16;           // 0,16,48,112
    int kk = 8 >> s;              // 8,4,2,1
    int j = l - off;
    int bs_i = b >> 5, c_i = b & 31;
    __shared__ float xv[16];
    int t = threadIdx.x;
    if (t < 16) {
        int tau = (j * 16 + t) * kk;
        xv[t] = x_enc[((size_t)bs_i * 2048 + tau) * 32 + c_i];
    }
    __syncthreads();
    int pe_row = j * kk;
    const float NEG2LN = -0.035977892078032f; // -2*ln(10000)/512
    for (int d = t; d < 512; d += 256) {
        float acc = 0.f;
        #pragma unroll
        for (int i = 0; i < 16; ++i) acc += xv[i] * W_emb[i * 512 + d];
        int di = d >> 1;
        float ang = (float)pe_row * expf((float)di * NEG2LN);
        float pos = (d & 1) ? cosf(ang) : sinf(ang);
        h[(size_t)row * 512 + d] = __float2bfloat16(acc + pos);
    }
}

// ---------------------------------------------------------------- GEMM: C[M,N] = A[M,K] @ Bt[N,K]^T + bias (+gelu)
// 256x256 tile, BK=32, 8 waves (2M x 4N), FOUR LDS slots (4 x 32 KiB = 128 KiB):
// prefetch depth = 3 K-tiles (~1200 cyc in flight >= HBM latency ~900), counted
// s_waitcnt vmcnt(12) steady-state (never 0 until drain), 2 barriers/tile,
// 32 MFMA per barrier-pair, 2-bit XOR chunk swizzle (conflict-free-beyond-minimum
// b128 reads), bijective XCD-chunk blockIdx swizzle. No setprio (m190: null/neg
// without wave role-split). Epilogue: acc -> LDS (all 4 slots = exactly the
// 256x256 bf16 C tile) -> coalesced global_store_dwordx4 (verified r7: WRITE_SIZE
// at ideal, eliminates 2x partial-sector write amplification).
// Requires: M%256==0, N%256==0, K%32==0, K>=128, gridDim.x*gridDim.y % 8 == 0.
__global__ __launch_bounds__(512, 2) void gemm_bt_256(const bf16* __restrict__ A,
                                                      const bf16* __restrict__ Bt,
                                                      const float* __restrict__ bias,
                                                      bf16* __restrict__ C,
                                                      int M, int N, int K, int act) {
    __shared__ __align__(16) bf16 smem[4 * 16384];   // slot s: A 256x32 @ s*16384, B 256x32 @ +8192
    const int t = threadIdx.x;
    const int wave = t >> 6, lane = t & 63;
    const int quad = lane >> 4, l16 = lane & 15;

    // XCD-aware chunked swizzle (all grids used here have nwg % 8 == 0 -> bijective)
    const int nwg = gridDim.x * gridDim.y;
    const int id = blockIdx.y * gridDim.x + blockIdx.x;
    const int swz = (id & 7) * (nwg >> 3) + (id >> 3);
    const int bx = swz % gridDim.x, by = swz / gridDim.x;
    const int m0 = by * 256, n0 = bx * 256;

    const int wm = (wave >> 2) * 128;   // 2 waves across M
    const int wn = (wave & 3) * 64;     // 4 waves across N

    f32x4 acc[8][4];
    #pragma unroll
    for (int a = 0; a < 8; ++a)
        #pragma unroll
        for (int b = 0; b < 4; ++b)
            #pragma unroll
            for (int r = 0; r < 4; ++r) acc[a][b][r] = 0.0f;

    // staging: per K-tile per wave: 2 issues for A + 2 for B (1 KiB each).
    // issue p covers rows [wave*32 + p*16 .. +15]; lane -> (srow = lane>>2, chunk = lane&3),
    // source chunk XOR'd by row&3 so LDS[row][c] = global[row][c ^ (row&3)]
    // (read side: lanes want chunk quad at rows base+l16; addr chunk quad^(l16&3) -> conflict-free).
    const int srow = lane >> 2;            // 0..15
    const int schunk = (lane & 3) ^ (srow & 3);
    const bf16* Abase = A + (size_t)(m0 + wave * 32 + srow) * K + schunk * 8;
    const bf16* Bbase = Bt + (size_t)(n0 + wave * 32 + srow) * K + schunk * 8;
    const int dst0 = wave * 1024 + lane * 8;     // elems; +512 for p=1; +8192 for B

#define STAGE_TILE(kt_, slot_)                                                          \
    {                                                                                   \
        bf16* Ad = smem + (slot_) * 16384;                                              \
        const size_t ko = (size_t)(kt_) * 32;                                           \
        GLOBAL_LOAD_LDS16(Abase + ko,                    Ad + dst0);                    \
        GLOBAL_LOAD_LDS16(Abase + (size_t)16 * K + ko,   Ad + dst0 + 512);              \
        GLOBAL_LOAD_LDS16(Bbase + ko,                    Ad + 8192 + dst0);             \
        GLOBAL_LOAD_LDS16(Bbase + (size_t)16 * K + ko,   Ad + 8192 + dst0 + 512);       \
    }

    const int NK = K >> 5;
    // prologue: tiles 0,1,2 into slots 0,1,2 (12 issues/wave, FIFO-grouped by tile)
    STAGE_TILE(0, 0);
    STAGE_TILE(1, 1);
    STAGE_TILE(2, 2);

    const int rsw = (quad ^ (l16 & 3)) << 3;     // read chunk byte offset /2 (elems)

    for (int kt = 0; kt < NK; ++kt) {
        const bf16* As = smem + (kt & 3) * 16384;
        const bf16* Bs = As + 8192;
        if (kt + 3 < NK) STAGE_TILE(kt + 3, (kt + 3) & 3);
        // counted drain: retire exactly tile kt's 4 loads (FIFO-oldest); keep up to 12 in flight
        const int rem = NK - 1 - kt;
        if (rem >= 3)      asm volatile("s_waitcnt vmcnt(12)" ::: "memory");
        else if (rem == 2) asm volatile("s_waitcnt vmcnt(8)" ::: "memory");
        else if (rem == 1) asm volatile("s_waitcnt vmcnt(4)" ::: "memory");
        else               asm volatile("s_waitcnt vmcnt(0)" ::: "memory");
        asm volatile("s_barrier" ::: "memory");   // all waves' tile-kt staging visible

        bf16x8 af[8], bq[4];
        #pragma unroll
        for (int mi = 0; mi < 8; ++mi)
            af[mi] = *(const bf16x8*)&As[(wm + mi * 16 + l16) * 32 + rsw];
        #pragma unroll
        for (int ni = 0; ni < 4; ++ni)
            bq[ni] = *(const bf16x8*)&Bs[(wn + ni * 16 + l16) * 32 + rsw];
        #pragma unroll
        for (int mi = 0; mi < 8; ++mi)
            #pragma unroll
            for (int ni = 0; ni < 4; ++ni)
                acc[mi][ni] = __builtin_amdgcn_mfma_f32_16x16x32_bf16(af[mi], bq[ni],
                                                                     acc[mi][ni], 0, 0, 0);
        asm volatile("s_barrier" ::: "memory");   // reads of slot kt done -> writable at kt+1 top
    }
#undef STAGE_TILE

    // ---------------- epilogue: stage C tile through LDS, then coalesced 16B stores.
    // smem (128 KiB) is dead after the K-loop and is exactly one 256x256 bf16 tile.
    // Layout: byte_off(row,col) = row*512 + ((col>>3) ^ (row&31))*16 + (col&7)*2
    // (verified r7: WRITE_SIZE drops to ideal; residual LDS-conflict count is the
    // structural b128 minimum, not avoidable cost).
    {
        char* ctile = (char*)smem;
        const int oddl = l16 & 1;
        #pragma unroll
        for (int ni = 0; ni < 4; ++ni) {
            int colt = wn + ni * 16 + l16;          // tile col 0..255
            float bv = bias[n0 + colt];
            #pragma unroll
            for (int mi = 0; mi < 8; ++mi) {
                float v0 = acc[mi][ni][0] + bv;
                float v1 = acc[mi][ni][1] + bv;
                float v2 = acc[mi][ni][2] + bv;
                float v3 = acc[mi][ni][3] + bv;
                if (act) {
                    v0 = gelu_f(v0); v1 = gelu_f(v1);
                    v2 = gelu_f(v2); v3 = gelu_f(v3);
                }
                // adjacent l16 lanes hold adjacent cols of the same rows -> pair via shfl_xor(1)
                float p0 = __shfl_xor(v0, 1);
                float p1 = __shfl_xor(v1, 1);
                float p2 = __shfl_xor(v2, 1);
                float p3 = __shfl_xor(v3, 1);
                float lo0 = oddl ? p1 : v0, hi0 = oddl ? v1 : p0;
                float lo1 = oddl ? p3 : v2, hi1 = oddl ? v3 : p2;
                int rowt0 = wm + mi * 16 + quad * 4 + oddl;   // rows +0/+1
                int rowt1 = rowt0 + 2;                        // rows +2/+3
                int colp = colt & ~1;
                *(unsigned*)(ctile + rowt0 * 512 + ((((colp >> 3) ^ (rowt0 & 31)) << 4) | ((colp & 7) << 1)))
                    = pack_bf16(lo0, hi0);
                *(unsigned*)(ctile + rowt1 * 512 + ((((colp >> 3) ^ (rowt1 & 31)) << 4) | ((colp & 7) << 1)))
                    = pack_bf16(lo1, hi1);
            }
        }
        __syncthreads();
        // read out: 16 rounds; per round 512 threads cover 16 rows x 512B, each row
        // written as 32 contiguous dwordx4 (fully coalesced, no partial sectors)
        const int rsub = t >> 5;    // 0..15
        const int cch = t & 31;     // 16B chunk 0..31
        #pragma unroll
        for (int g = 0; g < 16; ++g) {
            int row = g * 16 + rsub;
            bf16x8 v = *(const bf16x8*)(ctile + row * 512 + ((cch ^ (row & 31)) << 4));
            *(bf16x8*)(C + (size_t)(m0 + row) * N + n0 + cch * 8) = v;
        }
    }
}

// ---------------------------------------------------------------- MFMA segment attention (qkv fused input, stride 1536)
template<int LEN>
__global__ __launch_bounds__(256) void attn_mfma(const bf16* __restrict__ qkv,
                                                 const bf16* __restrict__ vt,
                                                 bf16* __restrict__ o) {
    constexpr int NT = LEN / 16;
    constexpr int KT = (LEN >= 32) ? (LEN / 32) : 1;
    constexpr int PST = (LEN == 16) ? 40 : (LEN + 8);
    constexpr int SLABS = LEN / 16;
    constexpr int OFF = LEN - 16;
    __shared__ __align__(16) bf16 Plds[4 * 16 * PST];

    const int t = threadIdx.x;
    const int wave = t >> 6, lane = t & 63;
    const int quad = lane >> 4, l16 = lane & 15;
    const int task = blockIdx.x * 4 + wave;
    const int b = task / (8 * SLABS);
    const int rem = task - b * (8 * SLABS);
    const int h = rem / SLABS;
    const int slab = rem - h * SLABS;

    const size_t qbase = ((size_t)b * 240 + OFF) * 1536 + h * 64;
    const size_t obase = ((size_t)b * 240 + OFF) * 512 + h * 64;

    const bf16* qp = qkv + qbase + (size_t)(slab * 16 + l16) * 1536 + quad * 8;
    bf16x8 qf0 = *(const bf16x8*)qp;
    bf16x8 qf1 = *(const bf16x8*)(qp + 32);

    f32x4 sacc[NT];
    #pragma unroll
    for (int nt = 0; nt < NT; ++nt) {
        const bf16* kp = qkv + qbase + 512 + (size_t)(nt * 16 + l16) * 1536 + quad * 8;
        bf16x8 kf0 = *(const bf16x8*)kp;
        bf16x8 kf1 = *(const bf16x8*)(kp + 32);
        f32x4 a = {0.f, 0.f, 0.f, 0.f};
        a = __builtin_amdgcn_mfma_f32_16x16x32_bf16(qf0, kf0, a, 0, 0, 0);
        a = __builtin_amdgcn_mfma_f32_16x16x32_bf16(qf1, kf1, a, 0, 0, 0);
        sacc[nt] = a;
    }

    float mx[4], sm[4];
    #pragma unroll
    for (int r = 0; r < 4; ++r) mx[r] = -3.0e38f;
    #pragma unroll
    for (int nt = 0; nt < NT; ++nt)
        #pragma unroll
        for (int r = 0; r < 4; ++r) {
            sacc[nt][r] *= 0.125f;
            mx[r] = fmaxf(mx[r], sacc[nt][r]);
        }
    #pragma unroll
    for (int msk = 1; msk < 16; msk <<= 1)
        #pragma unroll
        for (int r = 0; r < 4; ++r) mx[r] = fmaxf(mx[r], __shfl_xor(mx[r], msk));
    #pragma unroll
    for (int r = 0; r < 4; ++r) sm[r] = 0.f;
    #pragma unroll
    for (int nt = 0; nt < NT; ++nt)
        #pragma unroll
        for (int r = 0; r < 4; ++r) {
            float p = __expf(sacc[nt][r] - mx[r]);
            sacc[nt][r] = p;
            sm[r] += p;
        }
    #pragma unroll
    for (int msk = 1; msk < 16; msk <<= 1)
        #pragma unroll
        for (int r = 0; r < 4; ++r) sm[r] += __shfl_xor(sm[r], msk);
    float inv[4];
    #pragma unroll
    for (int r = 0; r < 4; ++r) inv[r] = 1.f / sm[r];

    bf16* pw = Plds + wave * 16 * PST;
    #pragma unroll
    for (int nt = 0; nt < NT; ++nt)
        #pragma unroll
        for (int r = 0; r < 4; ++r)
            pw[(quad * 4 + r) * PST + nt * 16 + l16] =
                __float2bfloat16(sacc[nt][r] * inv[r]);
    if (LEN == 16) {
        #pragma unroll
        for (int r = 0; r < 4; ++r)
            pw[(quad * 4 + r) * PST + 16 + l16] = __float2bfloat16(0.f);
    }
    __syncthreads();

    f32x4 oacc[4];
    #pragma unroll
    for (int n4 = 0; n4 < 4; ++n4) {
        f32x4 z = {0.f, 0.f, 0.f, 0.f};
        oacc[n4] = z;
    }
    #pragma unroll
    for (int kt = 0; kt < KT; ++kt) {
        bf16x8 pf = *(const bf16x8*)&pw[l16 * PST + kt * 32 + quad * 8];
        #pragma unroll
        for (int n4 = 0; n4 < 4; ++n4) {
            const bf16* vp = vt + ((size_t)b * 512 + h * 64 + n4 * 16 + l16) * 240
                              + OFF + kt * 32 + quad * 8;
            bf16x8 vf = *(const bf16x8*)vp;
            oacc[n4] = __builtin_amdgcn_mfma_f32_16x16x32_bf16(pf, vf, oacc[n4], 0, 0, 0);
        }
    }
    #pragma unroll
    for (int n4 = 0; n4 < 4; ++n4)
        #pragma unroll
        for (int r = 0; r < 4; ++r)
            o[obase + (size_t)(slab * 16 + quad * 4 + r) * 512 + n4 * 16 + l16] =
                __float2bfloat16(oacc[n4][r]);
}

// ---------------------------------------------------------------- residual + layernorm (row = 512)
__global__ __launch_bounds__(256) void ln_kernel(const bf16* x, const bf16* res,
                                                 const float* __restrict__ g,
                                                 const float* __restrict__ bta,
                                                 bf16* out_bf, float* out_f) {
    int row = blockIdx.x;
    int t = threadIdx.x;
    const bf16* xr = x + (size_t)row * 512;
    float v0 = __bfloat162float(xr[t]);
    float v1 = __bfloat162float(xr[t + 256]);
    if (res) {
        const bf16* rr = res + (size_t)row * 512;
        v0 += __bfloat162float(rr[t]);
        v1 += __bfloat162float(rr[t + 256]);
    }
    float s = v0 + v1, ss = v0 * v0 + v1 * v1;
    #pragma unroll
    for (int mk = 1; mk < 64; mk <<= 1) { s += __shfl_xor(s, mk); ss += __shfl_xor(ss, mk); }
    __shared__ float red[8];
    int wave = t >> 6, lane = t & 63;
    if (lane == 0) { red[wave * 2] = s; red[wave * 2 + 1] = ss; }
    __syncthreads();
    s = red[0] + red[2] + red[4] + red[6];
    ss = red[1] + red[3] + red[5] + red[7];
    float mu = s * (1.f / 512.f);
    float var = ss * (1.f / 512.f) - mu * mu;
    float inv = rsqrtf(var + 1e-5f);
    float y0 = (v0 - mu) * inv * g[t] + bta[t];
    float y1 = (v1 - mu) * inv * g[t + 256] + bta[t + 256];
    if (out_bf) {
        bf16* orow = out_bf + (size_t)row * 512;
        orow[t] = __float2bfloat16(y0);
        orow[t + 256] = __float2bfloat16(y1);
    } else {
        float* orow = out_f + (size_t)row * 512;
        orow[t] = y0;
        orow[t + 256] = y1;
    }
}

// ---------------------------------------------------------------- launch
extern "C" void kernel_launch(void* const* d_in, const int* in_sizes, int n_in,
                              void* d_out, int out_size, void* d_ws, size_t ws_size,
                              hipStream_t stream) {
    const float* x_enc = (const float*)d_in[0];
    const float* W_emb = (const float*)d_in[1];
    const float* Wq    = (const float*)d_in[2];
    const float* bq    = (const float*)d_in[3];
    const float* Wk    = (const float*)d_in[4];
    const float* bk    = (const float*)d_in[5];
    const float* Wv    = (const float*)d_in[6];
    const float* bv    = (const float*)d_in[7];
    const float* Wo    = (const float*)d_in[8];
    const float* bo    = (const float*)d_in[9];
    const float* ln1_g = (const float*)d_in[10];
    const float* ln1_b = (const float*)d_in[11];
    const float* W1    = (const float*)d_in[12];
    const float* b1    = (const float*)d_in[13];
    const float* W2    = (const float*)d_in[14];
    const float* b2    = (const float*)d_in[15];
    const float* ln2_g = (const float*)d_in[16];
    const float* ln2_b = (const float*)d_in[17];
    const float* lnf_g = (const float*)d_in[18];
    const float* lnf_b = (const float*)d_in[19];

    const int ROWS = 256 * 240;            // 61440
    char* ws = (char*)d_ws;
    const size_t Hb = (size_t)ROWS * 512 * 2;  // 62,914,560 B
    bf16* h    = (bf16*)(ws);
    bf16* qkv  = (bf16*)(ws + Hb);         // [ROWS][1536]; q|k|v
    bf16* oa   = (bf16*)(ws + 4 * Hb);     // attention output [ROWS][512]
    bf16* scr2 = (bf16*)(ws + 5 * Hb);     // vt during attn; oproj; ffnout
    bf16* mid  = qkv;                      // FFN mid [ROWS][2048] aliases qkv+oa (4*Hb)
    bf16* WqkvT = (bf16*)(ws + 6 * Hb);    // [L][1536][512]
    bf16* WoT  = WqkvT + (size_t)3 * 1536 * 512;
    bf16* W1T  = WoT + (size_t)3 * 512 * 512;
    bf16* W2T  = W1T + (size_t)3 * 512 * 2048;
    float* bcat = (float*)(W2T + (size_t)3 * 2048 * 512);   // [L][1536]

    bf16* vt     = scr2;
    bf16* oproj  = scr2;
    bf16* ffnout = scr2;

    dim3 blk(256);
    dim3 gblk(512);
    transpose_f32_bf16<<<dim3(16, 16, 3), blk, 0, stream>>>(Wq, WqkvT, 512, 512, (size_t)1536 * 512);
    transpose_f32_bf16<<<dim3(16, 16, 3), blk, 0, stream>>>(Wk, WqkvT + (size_t)512 * 512, 512, 512, (size_t)1536 * 512);
    transpose_f32_bf16<<<dim3(16, 16, 3), blk, 0, stream>>>(Wv, WqkvT + (size_t)1024 * 512, 512, 512, (size_t)1536 * 512);
    transpose_f32_bf16<<<dim3(16, 16, 3), blk, 0, stream>>>(Wo, WoT, 512, 512, (size_t)512 * 512);
    transpose_f32_bf16<<<dim3(64, 16, 3), blk, 0, stream>>>(W1, W1T, 512, 2048, (size_t)512 * 2048);
    transpose_f32_bf16<<<dim3(16, 64, 3), blk, 0, stream>>>(W2, W2T, 2048, 512, (size_t)2048 * 512);
    concat_bias<<<18, blk, 0, stream>>>(bq, bk, bv, bcat);

    embed_kernel<<<ROWS, blk, 0, stream>>>(x_enc, W_emb, h);

    for (int L = 0; L < 3; ++L) {
        size_t wo = (size_t)L * 512 * 512;
        size_t w1o = (size_t)L * 512 * 2048;
        gemm_bt_256<<<dim3(6, 240), gblk, 0, stream>>>(h, WqkvT + (size_t)L * 1536 * 512,
                                                       bcat + L * 1536, qkv, ROWS, 1536, 512, 0);
        transpose_v<<<dim3(16, 8, 256), blk, 0, stream>>>(qkv, vt);
        attn_mfma<16><<<512, blk, 0, stream>>>(qkv, vt, oa);
        attn_mfma<32><<<1024, blk, 0, stream>>>(qkv, vt, oa);
        attn_mfma<64><<<2048, blk, 0, stream>>>(qkv, vt, oa);
        attn_mfma<128><<<4096, blk, 0, stream>>>(qkv, vt, oa);
        gemm_bt_256<<<dim3(2, 240), gblk, 0, stream>>>(oa, WoT + wo, bo + L * 512, oproj, ROWS, 512, 512, 0);
        ln_kernel<<<ROWS, blk, 0, stream>>>(h, oproj, ln1_g + L * 512, ln1_b + L * 512, h, nullptr);
        gemm_bt_256<<<dim3(8, 240), gblk, 0, stream>>>(h, W1T + w1o, b1 + L * 2048, mid, ROWS, 2048, 512, 1);
        gemm_bt_256<<<dim3(2, 240), gblk, 0, stream>>>(mid, W2T + w1o, b2 + L * 512, ffnout, ROWS, 512, 2048, 0);
        ln_kernel<<<ROWS, blk, 0, stream>>>(h, ffnout, ln2_g + L * 512, ln2_b + L * 512, h, nullptr);
    }
    ln_kernel<<<ROWS, blk, 0, stream>>>(h, nullptr, lnf_g, lnf_b, nullptr, (float*)d_out);
}

// Round 15
// 2672.783 us; speedup vs baseline: 1.1207x; 1.1207x over previous
//
#include <hip/hip_runtime.h>
#include <hip/hip_bf16.h>

typedef short bf16x8 __attribute__((ext_vector_type(8)));
typedef float f32x4 __attribute__((ext_vector_type(4)));
using bf16 = __hip_bfloat16;

#define GLOBAL_LOAD_LDS16(g, l)                                                          \
    __builtin_amdgcn_global_load_lds((const __attribute__((address_space(1))) unsigned int*)(g), \
                                     (__attribute__((address_space(3))) unsigned int*)(l), \
                                     16, 0, 0)

// ---------------------------------------------------------------- utilities
static __device__ __forceinline__ float gelu_f(float x) {
    float u = 1.5957691216057308f * x * (1.0f + 0.044715f * x * x);
    return x / (1.0f + __expf(-u));
}

static __device__ __forceinline__ unsigned pack_bf16(float lo, float hi) {
    union { bf16 h; unsigned short u; } a, b;
    a.h = __float2bfloat16(lo);
    b.h = __float2bfloat16(hi);
    return ((unsigned)b.u << 16) | (unsigned)a.u;
}

// ---------------------------------------------------------------- transpose + downcast (f32 -> bf16), batched over z
__global__ __launch_bounds__(256) void transpose_f32_bf16(const float* __restrict__ in,
                                                          bf16* __restrict__ out,
                                                          int R, int C, size_t zso) {
    __shared__ float tile[32][33];
    size_t zi = (size_t)blockIdx.z * R * C;
    size_t zo = (size_t)blockIdx.z * zso;
    int c0 = blockIdx.x * 32, r0 = blockIdx.y * 32;
    int tx = threadIdx.x & 31, ty = threadIdx.x >> 5;
    #pragma unroll
    for (int i = 0; i < 32; i += 8) {
        int r = r0 + ty + i, c = c0 + tx;
        if (r < R && c < C) tile[ty + i][tx] = in[zi + (size_t)r * C + c];
    }
    __syncthreads();
    #pragma unroll
    for (int i = 0; i < 32; i += 8) {
        int c = c0 + ty + i, r = r0 + tx;
        if (c < C && r < R) out[zo + (size_t)c * R + r] = __float2bfloat16(tile[tx][ty + i]);
    }
}

// ---------------------------------------------------------------- bias concat: [L][1536] = bq|bk|bv
__global__ __launch_bounds__(256) void concat_bias(const float* __restrict__ bq,
                                                   const float* __restrict__ bk,
                                                   const float* __restrict__ bv,
                                                   float* __restrict__ out) {
    int i = blockIdx.x * 256 + threadIdx.x;
    if (i < 3 * 1536) {
        int L = i / 1536, r = i - L * 1536;
        float v = (r < 512) ? bq[L * 512 + r]
                : (r < 1024) ? bk[L * 512 + r - 512]
                             : bv[L * 512 + r - 1024];
        out[i] = v;
    }
}

// ---------------------------------------------------------------- V transpose: qkv[b*240+t][1536] (cols 1024..1535) -> vt[b*512+d][240]
__global__ __launch_bounds__(256) void transpose_v(const bf16* __restrict__ in,
                                                   bf16* __restrict__ out) {
    __shared__ bf16 tile[32][33];
    int b = blockIdx.z;
    int d0 = blockIdx.x * 32, t0 = blockIdx.y * 32;
    int tx = threadIdx.x & 31, ty = threadIdx.x >> 5;
    #pragma unroll
    for (int i = 0; i < 32; i += 8) {
        int tt = t0 + ty + i, dd = d0 + tx;
        if (tt < 240) tile[ty + i][tx] = in[((size_t)b * 240 + tt) * 1536 + 1024 + dd];
    }
    __syncthreads();
    #pragma unroll
    for (int i = 0; i < 32; i += 8) {
        int dd = d0 + ty + i, tt = t0 + tx;
        if (tt < 240) out[((size_t)b * 512 + dd) * 240 + tt] = tile[tx][ty + i];
    }
}

// ---------------------------------------------------------------- positional-encoding table: petab[pr][d], pr in 0..239
__global__ __launch_bounds__(256) void pe_table(float* __restrict__ petab) {
    int pr = blockIdx.x;
    int t = threadIdx.x;
    const float NEG2LN = -0.035977892078032f; // -2*ln(10000)/512
    for (int d = t; d < 512; d += 256) {
        int di = d >> 1;
        float ang = (float)pr * expf((float)di * NEG2LN);
        petab[pr * 512 + d] = (d & 1) ? cosf(ang) : sinf(ang);
    }
}

// ---------------------------------------------------------------- patch embedding + positional encoding (table-driven)
__global__ __launch_bounds__(256) void embed_kernel(const float* __restrict__ x_enc,
                                                    const float* __restrict__ W_emb, // [16][512]
                                                    const float* __restrict__ petab, // [240][512]
                                                    bf16* __restrict__ h) {
    int row = blockIdx.x;
    int b = row / 240, l = row - b * 240;
    int s = (l < 16) ? 0 : (l < 48) ? 1 : (l < 112) ? 2 : 3;
    int len = 16 << s;
    int off = len - 16;           // 0,16,48,112
    int kk = 8 >> s;              // 8,4,2,1
    int j = l - off;
    int bs_i = b >> 5, c_i = b & 31;
    __shared__ float xv[16];
    int t = threadIdx.x;
    if (t < 16) {
        int tau = (j * 16 + t) * kk;
        xv[t] = x_enc[((size_t)bs_i * 2048 + tau) * 32 + c_i];
    }
    __syncthreads();
    int pe_row = j * kk;
    for (int d = t; d < 512; d += 256) {
        float acc = 0.f;
        #pragma unroll
        for (int i = 0; i < 16; ++i) acc += xv[i] * W_emb[i * 512 + d];
        h[(size_t)row * 512 + d] = __float2bfloat16(acc + petab[pe_row * 512 + d]);
    }
}

// ---------------------------------------------------------------- GEMM: C[M,N] = A[M,K] @ Bt[N,K]^T + bias (+gelu)
// 256x256 tile, BK=64, 8 waves (2M x 4N), double-buffered LDS (2 K-tile slots, 128 KiB),
// deep pipeline: counted s_waitcnt vmcnt(4) (never 0 in main loop), 4-phase
// ds_read || global_load_lds || MFMA interleave per K-tile, raw s_barrier,
// setprio(1) around each 16-MFMA cluster, 3-bit XOR chunk swizzle (conflict-free b128),
// bijective XCD-chunk blockIdx swizzle.  [r7-measured best main loop: 2735 us total]
// Epilogue (A/B-measured r6 vs r7): act=1 (FFN1, compute-limited) -> scattered paired-dword
// stores (r6: FFN1 231 us vs staged 245); act=0 -> LDS-staged coalesced dwordx4 stores
// (r7: -152 us on the N=512/QKV dispatches via ideal WRITE_SIZE).
// Requires: M%256==0, N%256==0, K%64==0, K>=128, gridDim.x*gridDim.y % 8 == 0.
__global__ __launch_bounds__(512, 2) void gemm_bt_256(const bf16* __restrict__ A,
                                                      const bf16* __restrict__ Bt,
                                                      const float* __restrict__ bias,
                                                      bf16* __restrict__ C,
                                                      int M, int N, int K, int act) {
    __shared__ __align__(16) bf16 smem[2 * 32768];   // [slot][A 256x64 | B 256x64]
    const int t = threadIdx.x;
    const int wave = t >> 6, lane = t & 63;
    const int quad = lane >> 4, l16 = lane & 15;
    const int axor = l16 & 7;

    // XCD-aware chunked swizzle (all grids used here have nwg % 8 == 0 -> bijective)
    const int nwg = gridDim.x * gridDim.y;
    const int id = blockIdx.y * gridDim.x + blockIdx.x;
    const int swz = (id & 7) * (nwg >> 3) + (id >> 3);
    const int bx = swz % gridDim.x, by = swz / gridDim.x;
    const int m0 = by * 256, n0 = bx * 256;

    const int wm = (wave >> 2) * 128;   // 2 waves across M
    const int wn = (wave & 3) * 64;     // 4 waves across N

    f32x4 acc[8][4];
    #pragma unroll
    for (int a = 0; a < 8; ++a)
        #pragma unroll
        for (int b = 0; b < 4; ++b)
            #pragma unroll
            for (int r = 0; r < 4; ++r) acc[a][b][r] = 0.0f;

    // staging: per wave, 4 issues/matrix/K-tile; lane -> (row = lane>>3, chunk = lane&7),
    // source chunk XOR'd by row so LDS[r][c] holds data chunk c^(r&7) (read-side conflict-free)
    const int srow = lane >> 3;
    const int schunk = (lane & 7) ^ srow;
    const bf16* Abase = A + (size_t)(m0 + wave * 32 + srow) * K + schunk * 8;
    const bf16* Bbase = Bt + (size_t)(n0 + wave * 32 + srow) * K + schunk * 8;

    // prologue: stage K-tile 0 into slot 0 (8 issues/wave outstanding)
    #pragma unroll
    for (int p = 0; p < 4; ++p)
        GLOBAL_LOAD_LDS16(Abase + (size_t)(p * 8) * K, smem + (wave * 4 + p) * 512);
    #pragma unroll
    for (int p = 0; p < 4; ++p)
        GLOBAL_LOAD_LDS16(Bbase + (size_t)(p * 8) * K, smem + 16384 + (wave * 4 + p) * 512);

    bf16x8 af[4][2], b0[2][2], b1[2][2];

#define BARRIER() asm volatile("s_barrier" ::: "memory")
#define LOAD_A(mq)                                                                    \
    _Pragma("unroll")                                                                 \
    for (int mi = 0; mi < 4; ++mi)                                                    \
        _Pragma("unroll")                                                             \
        for (int kk = 0; kk < 2; ++kk)                                                \
            af[mi][kk] = *(const bf16x8*)&Asl[(wm + (mq) * 64 + mi * 16 + l16) * 64   \
                                              + (((kk << 2) + quad) ^ axor) * 8];
#define LOAD_B(nq, dst)                                                               \
    _Pragma("unroll")                                                                 \
    for (int ni = 0; ni < 2; ++ni)                                                    \
        _Pragma("unroll")                                                             \
        for (int kk = 0; kk < 2; ++kk)                                                \
            dst[ni][kk] = *(const bf16x8*)&Bsl[(wn + (nq) * 32 + ni * 16 + l16) * 64  \
                                               + (((kk << 2) + quad) ^ axor) * 8];
#define MMA_Q(mo, no, src)                                                            \
    __builtin_amdgcn_s_setprio(1);                                                    \
    _Pragma("unroll")                                                                 \
    for (int mi = 0; mi < 4; ++mi)                                                    \
        _Pragma("unroll")                                                             \
        for (int ni = 0; ni < 2; ++ni)                                                \
            _Pragma("unroll")                                                         \
            for (int kk = 0; kk < 2; ++kk)                                            \
                acc[(mo) + mi][(no) + ni] = __builtin_amdgcn_mfma_f32_16x16x32_bf16(  \
                    af[mi][kk], src[ni][kk], acc[(mo) + mi][(no) + ni], 0, 0, 0);     \
    __builtin_amdgcn_s_setprio(0);

    const int NK = K >> 6;
    for (int kt = 0; kt < NK - 1; ++kt) {
        const int s = kt & 1;
        const bf16* Asl = smem + s * 32768;
        const bf16* Bsl = Asl + 16384;
        bf16* Asn = smem + (s ^ 1) * 32768;
        bf16* Bsn = Asn + 16384;
        const size_t kn = (size_t)(kt + 1) << 6;
        // pre-stage A of tile kt+1 (slot s^1 was fully read last iteration, behind barriers)
        #pragma unroll
        for (int p = 0; p < 4; ++p)
            GLOBAL_LOAD_LDS16(Abase + (size_t)(p * 8) * K + kn, Asn + (wave * 4 + p) * 512);
        // wait for tile kt's 8 loads (oldest); tile kt+1's 4 A-loads stay in flight
        asm volatile("s_waitcnt vmcnt(4)" ::: "memory");
        BARRIER();
        // ---- ph1: quadrant (0,0); stage B half 0 of tile kt+1
        LOAD_A(0); LOAD_B(0, b0);
        GLOBAL_LOAD_LDS16(Bbase + kn, Bsn + (wave * 4 + 0) * 512);
        GLOBAL_LOAD_LDS16(Bbase + (size_t)8 * K + kn, Bsn + (wave * 4 + 1) * 512);
        MMA_Q(0, 0, b0);
        BARRIER();
        // ---- ph2: quadrant (0,1); stage B half 1 of tile kt+1
        LOAD_B(1, b1);
        GLOBAL_LOAD_LDS16(Bbase + (size_t)16 * K + kn, Bsn + (wave * 4 + 2) * 512);
        GLOBAL_LOAD_LDS16(Bbase + (size_t)24 * K + kn, Bsn + (wave * 4 + 3) * 512);
        MMA_Q(0, 2, b1);
        BARRIER();
        // ---- ph3: quadrant (1,0) — last ds_reads of slot s
        LOAD_A(1);
        MMA_Q(4, 0, b0);
        BARRIER();   // all waves done reading slot s -> next iteration may overwrite it
        // ---- ph4: quadrant (1,1), register-only
        MMA_Q(4, 2, b1);
    }
    {   // peeled last K-tile: drain everything, no staging
        const bf16* Asl = smem + ((NK - 1) & 1) * 32768;
        const bf16* Bsl = Asl + 16384;
        asm volatile("s_waitcnt vmcnt(0)" ::: "memory");
        BARRIER();
        LOAD_A(0); LOAD_B(0, b0);
        MMA_Q(0, 0, b0);
        BARRIER();
        LOAD_B(1, b1);
        MMA_Q(0, 2, b1);
        BARRIER();
        LOAD_A(1);
        MMA_Q(4, 0, b0);
        BARRIER();
        MMA_Q(4, 2, b1);
    }
#undef BARRIER
#undef LOAD_A
#undef LOAD_B
#undef MMA_Q

    const int oddl = l16 & 1;
    if (act) {
        // ---------------- scattered paired-dword epilogue (r6-measured faster for FFN1)
        #pragma unroll
        for (int ni = 0; ni < 4; ++ni) {
            int col = n0 + wn + ni * 16 + l16;
            float bv = bias[col];
            #pragma unroll
            for (int mi = 0; mi < 8; ++mi) {
                float v0 = gelu_f(acc[mi][ni][0] + bv);
                float v1 = gelu_f(acc[mi][ni][1] + bv);
                float v2 = gelu_f(acc[mi][ni][2] + bv);
                float v3 = gelu_f(acc[mi][ni][3] + bv);
                float p0 = __shfl_xor(v0, 1);
                float p1 = __shfl_xor(v1, 1);
                float p2 = __shfl_xor(v2, 1);
                float p3 = __shfl_xor(v3, 1);
                float lo0 = oddl ? p1 : v0, hi0 = oddl ? v1 : p0;
                float lo1 = oddl ? p3 : v2, hi1 = oddl ? v3 : p2;
                int r0 = oddl ? 1 : 0;
                size_t rowb = (size_t)(m0 + wm + mi * 16 + quad * 4);
                unsigned* c0p = (unsigned*)(C + (rowb + r0) * N + (col & ~1));
                unsigned* c1p = (unsigned*)(C + (rowb + r0 + 2) * N + (col & ~1));
                *c0p = pack_bf16(lo0, hi0);
                *c1p = pack_bf16(lo1, hi1);
            }
        }
    } else {
        // ---------------- LDS-staged coalesced epilogue (r7-measured faster for act=0)
        // smem (128 KiB) is dead after the K-loop and is exactly one 256x256 bf16 tile.
        // byte_off(row,col) = row*512 + ((col>>3) ^ (row&31))*16 + (col&7)*2
        char* ctile = (char*)smem;
        #pragma unroll
        for (int ni = 0; ni < 4; ++ni) {
            int colt = wn + ni * 16 + l16;          // tile col 0..255
            float bv = bias[n0 + colt];
            #pragma unroll
            for (int mi = 0; mi < 8; ++mi) {
                float v0 = acc[mi][ni][0] + bv;
                float v1 = acc[mi][ni][1] + bv;
                float v2 = acc[mi][ni][2] + bv;
                float v3 = acc[mi][ni][3] + bv;
                float p0 = __shfl_xor(v0, 1);
                float p1 = __shfl_xor(v1, 1);
                float p2 = __shfl_xor(v2, 1);
                float p3 = __shfl_xor(v3, 1);
                float lo0 = oddl ? p1 : v0, hi0 = oddl ? v1 : p0;
                float lo1 = oddl ? p3 : v2, hi1 = oddl ? v3 : p2;
                int rowt0 = wm + mi * 16 + quad * 4 + oddl;   // rows +0/+1
                int rowt1 = rowt0 + 2;                        // rows +2/+3
                int colp = colt & ~1;
                *(unsigned*)(ctile + rowt0 * 512 + ((((colp >> 3) ^ (rowt0 & 31)) << 4) | ((colp & 7) << 1)))
                    = pack_bf16(lo0, hi0);
                *(unsigned*)(ctile + rowt1 * 512 + ((((colp >> 3) ^ (rowt1 & 31)) << 4) | ((colp & 7) << 1)))
                    = pack_bf16(lo1, hi1);
            }
        }
        __syncthreads();
        const int rsub = t >> 5;    // 0..15
        const int cch = t & 31;     // 16B chunk 0..31
        #pragma unroll
        for (int g = 0; g < 16; ++g) {
            int row = g * 16 + rsub;
            bf16x8 v = *(const bf16x8*)(ctile + row * 512 + ((cch ^ (row & 31)) << 4));
            *(bf16x8*)(C + (size_t)(m0 + row) * N + n0 + cch * 8) = v;
        }
    }
}

// ---------------------------------------------------------------- MFMA segment attention (qkv fused input, stride 1536)
template<int LEN>
__global__ __launch_bounds__(256) void attn_mfma(const bf16* __restrict__ qkv,
                                                 const bf16* __restrict__ vt,
                                                 bf16* __restrict__ o) {
    constexpr int NT = LEN / 16;
    constexpr int KT = (LEN >= 32) ? (LEN / 32) : 1;
    constexpr int PST = (LEN == 16) ? 40 : (LEN + 8);
    constexpr int SLABS = LEN / 16;
    constexpr int OFF = LEN - 16;
    __shared__ __align__(16) bf16 Plds[4 * 16 * PST];

    const int t = threadIdx.x;
    const int wave = t >> 6, lane = t & 63;
    const int quad = lane >> 4, l16 = lane & 15;
    const int task = blockIdx.x * 4 + wave;
    const int b = task / (8 * SLABS);
    const int rem = task - b * (8 * SLABS);
    const int h = rem / SLABS;
    const int slab = rem - h * SLABS;

    const size_t qbase = ((size_t)b * 240 + OFF) * 1536 + h * 64;
    const size_t obase = ((size_t)b * 240 + OFF) * 512 + h * 64;

    const bf16* qp = qkv + qbase + (size_t)(slab * 16 + l16) * 1536 + quad * 8;
    bf16x8 qf0 = *(const bf16x8*)qp;
    bf16x8 qf1 = *(const bf16x8*)(qp + 32);

    f32x4 sacc[NT];
    #pragma unroll
    for (int nt = 0; nt < NT; ++nt) {
        const bf16* kp = qkv + qbase + 512 + (size_t)(nt * 16 + l16) * 1536 + quad * 8;
        bf16x8 kf0 = *(const bf16x8*)kp;
        bf16x8 kf1 = *(const bf16x8*)(kp + 32);
        f32x4 a = {0.f, 0.f, 0.f, 0.f};
        a = __builtin_amdgcn_mfma_f32_16x16x32_bf16(qf0, kf0, a, 0, 0, 0);
        a = __builtin_amdgcn_mfma_f32_16x16x32_bf16(qf1, kf1, a, 0, 0, 0);
        sacc[nt] = a;
    }

    float mx[4], sm[4];
    #pragma unroll
    for (int r = 0; r < 4; ++r) mx[r] = -3.0e38f;
    #pragma unroll
    for (int nt = 0; nt < NT; ++nt)
        #pragma unroll
        for (int r = 0; r < 4; ++r) {
            sacc[nt][r] *= 0.125f;
            mx[r] = fmaxf(mx[r], sacc[nt][r]);
        }
    #pragma unroll
    for (int msk = 1; msk < 16; msk <<= 1)
        #pragma unroll
        for (int r = 0; r < 4; ++r) mx[r] = fmaxf(mx[r], __shfl_xor(mx[r], msk));
    #pragma unroll
    for (int r = 0; r < 4; ++r) sm[r] = 0.f;
    #pragma unroll
    for (int nt = 0; nt < NT; ++nt)
        #pragma unroll
        for (int r = 0; r < 4; ++r) {
            float p = __expf(sacc[nt][r] - mx[r]);
            sacc[nt][r] = p;
            sm[r] += p;
        }
    #pragma unroll
    for (int msk = 1; msk < 16; msk <<= 1)
        #pragma unroll
        for (int r = 0; r < 4; ++r) sm[r] += __shfl_xor(sm[r], msk);
    float inv[4];
    #pragma unroll
    for (int r = 0; r < 4; ++r) inv[r] = 1.f / sm[r];

    bf16* pw = Plds + wave * 16 * PST;
    #pragma unroll
    for (int nt = 0; nt < NT; ++nt)
        #pragma unroll
        for (int r = 0; r < 4; ++r)
            pw[(quad * 4 + r) * PST + nt * 16 + l16] =
                __float2bfloat16(sacc[nt][r] * inv[r]);
    if (LEN == 16) {
        #pragma unroll
        for (int r = 0; r < 4; ++r)
            pw[(quad * 4 + r) * PST + 16 + l16] = __float2bfloat16(0.f);
    }
    __syncthreads();

    f32x4 oacc[4];
    #pragma unroll
    for (int n4 = 0; n4 < 4; ++n4) {
        f32x4 z = {0.f, 0.f, 0.f, 0.f};
        oacc[n4] = z;
    }
    #pragma unroll
    for (int kt = 0; kt < KT; ++kt) {
        bf16x8 pf = *(const bf16x8*)&pw[l16 * PST + kt * 32 + quad * 8];
        #pragma unroll
        for (int n4 = 0; n4 < 4; ++n4) {
            const bf16* vp = vt + ((size_t)b * 512 + h * 64 + n4 * 16 + l16) * 240
                              + OFF + kt * 32 + quad * 8;
            bf16x8 vf = *(const bf16x8*)vp;
            oacc[n4] = __builtin_amdgcn_mfma_f32_16x16x32_bf16(pf, vf, oacc[n4], 0, 0, 0);
        }
    }
    #pragma unroll
    for (int n4 = 0; n4 < 4; ++n4)
        #pragma unroll
        for (int r = 0; r < 4; ++r)
            o[obase + (size_t)(slab * 16 + quad * 4 + r) * 512 + n4 * 16 + l16] =
                __float2bfloat16(oacc[n4][r]);
}

// ---------------------------------------------------------------- residual + layernorm (row = 512)
__global__ __launch_bounds__(256) void ln_kernel(const bf16* x, const bf16* res,
                                                 const float* __restrict__ g,
                                                 const float* __restrict__ bta,
                                                 bf16* out_bf, float* out_f) {
    int row = blockIdx.x;
    int t = threadIdx.x;
    const bf16* xr = x + (size_t)row * 512;
    float v0 = __bfloat162float(xr[t]);
    float v1 = __bfloat162float(xr[t + 256]);
    if (res) {
        const bf16* rr = res + (size_t)row * 512;
        v0 += __bfloat162float(rr[t]);
        v1 += __bfloat162float(rr[t + 256]);
    }
    float s = v0 + v1, ss = v0 * v0 + v1 * v1;
    #pragma unroll
    for (int mk = 1; mk < 64; mk <<= 1) { s += __shfl_xor(s, mk); ss += __shfl_xor(ss, mk); }
    __shared__ float red[8];
    int wave = t >> 6, lane = t & 63;
    if (lane == 0) { red[wave * 2] = s; red[wave * 2 + 1] = ss; }
    __syncthreads();
    s = red[0] + red[2] + red[4] + red[6];
    ss = red[1] + red[3] + red[5] + red[7];
    float mu = s * (1.f / 512.f);
    float var = ss * (1.f / 512.f) - mu * mu;
    float inv = rsqrtf(var + 1e-5f);
    float y0 = (v0 - mu) * inv * g[t] + bta[t];
    float y1 = (v1 - mu) * inv * g[t + 256] + bta[t + 256];
    if (out_bf) {
        bf16* orow = out_bf + (size_t)row * 512;
        orow[t] = __float2bfloat16(y0);
        orow[t + 256] = __float2bfloat16(y1);
    } else {
        float* orow = out_f + (size_t)row * 512;
        orow[t] = y0;
        orow[t + 256] = y1;
    }
}

// ---------------------------------------------------------------- launch
extern "C" void kernel_launch(void* const* d_in, const int* in_sizes, int n_in,
                              void* d_out, int out_size, void* d_ws, size_t ws_size,
                              hipStream_t stream) {
    const float* x_enc = (const float*)d_in[0];
    const float* W_emb = (const float*)d_in[1];
    const float* Wq    = (const float*)d_in[2];
    const float* bq    = (const float*)d_in[3];
    const float* Wk    = (const float*)d_in[4];
    const float* bk    = (const float*)d_in[5];
    const float* Wv    = (const float*)d_in[6];
    const float* bv    = (const float*)d_in[7];
    const float* Wo    = (const float*)d_in[8];
    const float* bo    = (const float*)d_in[9];
    const float* ln1_g = (const float*)d_in[10];
    const float* ln1_b = (const float*)d_in[11];
    const float* W1    = (const float*)d_in[12];
    const float* b1    = (const float*)d_in[13];
    const float* W2    = (const float*)d_in[14];
    const float* b2    = (const float*)d_in[15];
    const float* ln2_g = (const float*)d_in[16];
    const float* ln2_b = (const float*)d_in[17];
    const float* lnf_g = (const float*)d_in[18];
    const float* lnf_b = (const float*)d_in[19];

    const int ROWS = 256 * 240;            // 61440
    char* ws = (char*)d_ws;
    const size_t Hb = (size_t)ROWS * 512 * 2;  // 62,914,560 B
    bf16* h    = (bf16*)(ws);
    bf16* qkv  = (bf16*)(ws + Hb);         // [ROWS][1536]; q|k|v
    bf16* oa   = (bf16*)(ws + 4 * Hb);     // attention output [ROWS][512]
    bf16* scr2 = (bf16*)(ws + 5 * Hb);     // vt during attn; oproj; ffnout
    bf16* mid  = qkv;                      // FFN mid [ROWS][2048] aliases qkv+oa (4*Hb)
    bf16* WqkvT = (bf16*)(ws + 6 * Hb);    // [L][1536][512]
    bf16* WoT  = WqkvT + (size_t)3 * 1536 * 512;
    bf16* W1T  = WoT + (size_t)3 * 512 * 512;
    bf16* W2T  = W1T + (size_t)3 * 512 * 2048;
    float* bcat = (float*)(W2T + (size_t)3 * 2048 * 512);   // [L][1536]
    float* petab = bcat + 3 * 1536;                          // [240][512]

    bf16* vt     = scr2;
    bf16* oproj  = scr2;
    bf16* ffnout = scr2;

    dim3 blk(256);
    dim3 gblk(512);
    transpose_f32_bf16<<<dim3(16, 16, 3), blk, 0, stream>>>(Wq, WqkvT, 512, 512, (size_t)1536 * 512);
    transpose_f32_bf16<<<dim3(16, 16, 3), blk, 0, stream>>>(Wk, WqkvT + (size_t)512 * 512, 512, 512, (size_t)1536 * 512);
    transpose_f32_bf16<<<dim3(16, 16, 3), blk, 0, stream>>>(Wv, WqkvT + (size_t)1024 * 512, 512, 512, (size_t)1536 * 512);
    transpose_f32_bf16<<<dim3(16, 16, 3), blk, 0, stream>>>(Wo, WoT, 512, 512, (size_t)512 * 512);
    transpose_f32_bf16<<<dim3(64, 16, 3), blk, 0, stream>>>(W1, W1T, 512, 2048, (size_t)512 * 2048);
    transpose_f32_bf16<<<dim3(16, 64, 3), blk, 0, stream>>>(W2, W2T, 2048, 512, (size_t)2048 * 512);
    concat_bias<<<18, blk, 0, stream>>>(bq, bk, bv, bcat);
    pe_table<<<240, blk, 0, stream>>>(petab);

    embed_kernel<<<ROWS, blk, 0, stream>>>(x_enc, W_emb, petab, h);

    for (int L = 0; L < 3; ++L) {
        size_t wo = (size_t)L * 512 * 512;
        size_t w1o = (size_t)L * 512 * 2048;
        gemm_bt_256<<<dim3(6, 240), gblk, 0, stream>>>(h, WqkvT + (size_t)L * 1536 * 512,
                                                       bcat + L * 1536, qkv, ROWS, 1536, 512, 0);
        transpose_v<<<dim3(16, 8, 256), blk, 0, stream>>>(qkv, vt);
        attn_mfma<16><<<512, blk, 0, stream>>>(qkv, vt, oa);
        attn_mfma<32><<<1024, blk, 0, stream>>>(qkv, vt, oa);
        attn_mfma<64><<<2048, blk, 0, stream>>>(qkv, vt, oa);
        attn_mfma<128><<<4096, blk, 0, stream>>>(qkv, vt, oa);
        gemm_bt_256<<<dim3(2, 240), gblk, 0, stream>>>(oa, WoT + wo, bo + L * 512, oproj, ROWS, 512, 512, 0);
        ln_kernel<<<ROWS, blk, 0, stream>>>(h, oproj, ln1_g + L * 512, ln1_b + L * 512, h, nullptr);
        gemm_bt_256<<<dim3(8, 240), gblk, 0, stream>>>(h, W1T + w1o, b1 + L * 2048, mid, ROWS, 2048, 512, 1);
        gemm_bt_256<<<dim3(2, 240), gblk, 0, stream>>>(mid, W2T + w1o, b2 + L * 512, ffnout, ROWS, 512, 2048, 0);
        ln_kernel<<<ROWS, blk, 0, stream>>>(h, ffnout, ln2_g + L * 512, ln2_b + L * 512, h, nullptr);
    }
    ln_kernel<<<ROWS, blk, 0, stream>>>(h, nullptr, lnf_g, lnf_b, nullptr, (float*)d_out);
}

// Round 16
// 2482.072 us; speedup vs baseline: 1.2068x; 1.0768x over previous
//
#include <hip/hip_runtime.h>
#include <hip/hip_bf16.h>

typedef short bf16x8 __attribute__((ext_vector_type(8)));
typedef float f32x4 __attribute__((ext_vector_type(4)));
using bf16 = __hip_bfloat16;

#define GLOBAL_LOAD_LDS16(g, l)                                                          \
    __builtin_amdgcn_global_load_lds((const __attribute__((address_space(1))) unsigned int*)(g), \
                                     (__attribute__((address_space(3))) unsigned int*)(l), \
                                     16, 0, 0)

// ---------------------------------------------------------------- utilities
static __device__ __forceinline__ float gelu_f(float x) {
    float u = 1.5957691216057308f * x * (1.0f + 0.044715f * x * x);
    return x / (1.0f + __expf(-u));
}

static __device__ __forceinline__ unsigned pack_bf16(float lo, float hi) {
    union { bf16 h; unsigned short u; } a, b;
    a.h = __float2bfloat16(lo);
    b.h = __float2bfloat16(hi);
    return ((unsigned)b.u << 16) | (unsigned)a.u;
}

// ---------------------------------------------------------------- transpose + downcast (f32 -> bf16), batched over z
__global__ __launch_bounds__(256) void transpose_f32_bf16(const float* __restrict__ in,
                                                          bf16* __restrict__ out,
                                                          int R, int C, size_t zso) {
    __shared__ float tile[32][33];
    size_t zi = (size_t)blockIdx.z * R * C;
    size_t zo = (size_t)blockIdx.z * zso;
    int c0 = blockIdx.x * 32, r0 = blockIdx.y * 32;
    int tx = threadIdx.x & 31, ty = threadIdx.x >> 5;
    #pragma unroll
    for (int i = 0; i < 32; i += 8) {
        int r = r0 + ty + i, c = c0 + tx;
        if (r < R && c < C) tile[ty + i][tx] = in[zi + (size_t)r * C + c];
    }
    __syncthreads();
    #pragma unroll
    for (int i = 0; i < 32; i += 8) {
        int c = c0 + ty + i, r = r0 + tx;
        if (c < C && r < R) out[zo + (size_t)c * R + r] = __float2bfloat16(tile[tx][ty + i]);
    }
}

// ---------------------------------------------------------------- bias concat: [L][1536] = bq|bk|bv
__global__ __launch_bounds__(256) void concat_bias(const float* __restrict__ bq,
                                                   const float* __restrict__ bk,
                                                   const float* __restrict__ bv,
                                                   float* __restrict__ out) {
    int i = blockIdx.x * 256 + threadIdx.x;
    if (i < 3 * 1536) {
        int L = i / 1536, r = i - L * 1536;
        float v = (r < 512) ? bq[L * 512 + r]
                : (r < 1024) ? bk[L * 512 + r - 512]
                             : bv[L * 512 + r - 1024];
        out[i] = v;
    }
}

// ---------------------------------------------------------------- V transpose: qkv[b*240+t][1536] (cols 1024..1535) -> vt[b*512+d][240]
__global__ __launch_bounds__(256) void transpose_v(const bf16* __restrict__ in,
                                                   bf16* __restrict__ out) {
    __shared__ bf16 tile[32][33];
    int b = blockIdx.z;
    int d0 = blockIdx.x * 32, t0 = blockIdx.y * 32;
    int tx = threadIdx.x & 31, ty = threadIdx.x >> 5;
    #pragma unroll
    for (int i = 0; i < 32; i += 8) {
        int tt = t0 + ty + i, dd = d0 + tx;
        if (tt < 240) tile[ty + i][tx] = in[((size_t)b * 240 + tt) * 1536 + 1024 + dd];
    }
    __syncthreads();
    #pragma unroll
    for (int i = 0; i < 32; i += 8) {
        int dd = d0 + ty + i, tt = t0 + tx;
        if (tt < 240) out[((size_t)b * 512 + dd) * 240 + tt] = tile[tx][ty + i];
    }
}

// ---------------------------------------------------------------- positional-encoding table: petab[pr][d], pr in 0..239
__global__ __launch_bounds__(256) void pe_table(float* __restrict__ petab) {
    int pr = blockIdx.x;
    int t = threadIdx.x;
    const float NEG2LN = -0.035977892078032f; // -2*ln(10000)/512
    for (int d = t; d < 512; d += 256) {
        int di = d >> 1;
        float ang = (float)pr * expf((float)di * NEG2LN);
        petab[pr * 512 + d] = (d & 1) ? cosf(ang) : sinf(ang);
    }
}

// ---------------------------------------------------------------- patch embedding + positional encoding (table-driven)
__global__ __launch_bounds__(256) void embed_kernel(const float* __restrict__ x_enc,
                                                    const float* __restrict__ W_emb, // [16][512]
                                                    const float* __restrict__ petab, // [240][512]
                                                    bf16* __restrict__ h) {
    int row = blockIdx.x;
    int b = row / 240, l = row - b * 240;
    int s = (l < 16) ? 0 : (l < 48) ? 1 : (l < 112) ? 2 : 3;
    int len = 16 << s;
    int off = len - 16;           // 0,16,48,112
    int kk = 8 >> s;              // 8,4,2,1
    int j = l - off;
    int bs_i = b >> 5, c_i = b & 31;
    __shared__ float xv[16];
    int t = threadIdx.x;
    if (t < 16) {
        int tau = (j * 16 + t) * kk;
        xv[t] = x_enc[((size_t)bs_i * 2048 + tau) * 32 + c_i];
    }
    __syncthreads();
    int pe_row = j * kk;
    for (int d = t; d < 512; d += 256) {
        float acc = 0.f;
        #pragma unroll
        for (int i = 0; i < 16; ++i) acc += xv[i] * W_emb[i * 512 + d];
        h[(size_t)row * 512 + d] = __float2bfloat16(acc + petab[pe_row * 512 + d]);
    }
}

// ---------------------------------------------------------------- GEMM: C[M,N] = A[M,K] @ Bt[N,K]^T + bias (+gelu)
// 256x256 tile, BK=64, 8 waves (2M x 4N), double-buffered LDS (2 K-tile slots, 128 KiB),
// deep pipeline: counted s_waitcnt vmcnt(4) (never 0 in main loop), 4-phase
// ds_read || global_load_lds || MFMA interleave per K-tile, raw s_barrier,
// setprio(1) around each 16-MFMA cluster, 3-bit XOR chunk swizzle (conflict-free b128),
// bijective XCD-chunk blockIdx swizzle.  [r7/r15-measured best main loop]
// Epilogue (A/B-measured r6 vs r7): act=1 -> scattered paired-dword stores;
// act=0 -> LDS-staged coalesced dwordx4 stores.
// Requires: M%256==0, N%256==0, K%64==0, K>=128, gridDim.x*gridDim.y % 8 == 0.
__global__ __launch_bounds__(512, 2) void gemm_bt_256(const bf16* __restrict__ A,
                                                      const bf16* __restrict__ Bt,
                                                      const float* __restrict__ bias,
                                                      bf16* __restrict__ C,
                                                      int M, int N, int K, int act) {
    __shared__ __align__(16) bf16 smem[2 * 32768];   // [slot][A 256x64 | B 256x64]
    const int t = threadIdx.x;
    const int wave = t >> 6, lane = t & 63;
    const int quad = lane >> 4, l16 = lane & 15;
    const int axor = l16 & 7;

    // XCD-aware chunked swizzle (all grids used here have nwg % 8 == 0 -> bijective)
    const int nwg = gridDim.x * gridDim.y;
    const int id = blockIdx.y * gridDim.x + blockIdx.x;
    const int swz = (id & 7) * (nwg >> 3) + (id >> 3);
    const int bx = swz % gridDim.x, by = swz / gridDim.x;
    const int m0 = by * 256, n0 = bx * 256;

    const int wm = (wave >> 2) * 128;   // 2 waves across M
    const int wn = (wave & 3) * 64;     // 4 waves across N

    f32x4 acc[8][4];
    #pragma unroll
    for (int a = 0; a < 8; ++a)
        #pragma unroll
        for (int b = 0; b < 4; ++b)
            #pragma unroll
            for (int r = 0; r < 4; ++r) acc[a][b][r] = 0.0f;

    // staging: per wave, 4 issues/matrix/K-tile; lane -> (row = lane>>3, chunk = lane&7),
    // source chunk XOR'd by row so LDS[r][c] holds data chunk c^(r&7) (read-side conflict-free)
    const int srow = lane >> 3;
    const int schunk = (lane & 7) ^ srow;
    const bf16* Abase = A + (size_t)(m0 + wave * 32 + srow) * K + schunk * 8;
    const bf16* Bbase = Bt + (size_t)(n0 + wave * 32 + srow) * K + schunk * 8;

    // prologue: stage K-tile 0 into slot 0 (8 issues/wave outstanding)
    #pragma unroll
    for (int p = 0; p < 4; ++p)
        GLOBAL_LOAD_LDS16(Abase + (size_t)(p * 8) * K, smem + (wave * 4 + p) * 512);
    #pragma unroll
    for (int p = 0; p < 4; ++p)
        GLOBAL_LOAD_LDS16(Bbase + (size_t)(p * 8) * K, smem + 16384 + (wave * 4 + p) * 512);

    bf16x8 af[4][2], b0[2][2], b1[2][2];

#define BARRIER() asm volatile("s_barrier" ::: "memory")
#define LOAD_A(mq)                                                                    \
    _Pragma("unroll")                                                                 \
    for (int mi = 0; mi < 4; ++mi)                                                    \
        _Pragma("unroll")                                                             \
        for (int kk = 0; kk < 2; ++kk)                                                \
            af[mi][kk] = *(const bf16x8*)&Asl[(wm + (mq) * 64 + mi * 16 + l16) * 64   \
                                              + (((kk << 2) + quad) ^ axor) * 8];
#define LOAD_B(nq, dst)                                                               \
    _Pragma("unroll")                                                                 \
    for (int ni = 0; ni < 2; ++ni)                                                    \
        _Pragma("unroll")                                                             \
        for (int kk = 0; kk < 2; ++kk)                                                \
            dst[ni][kk] = *(const bf16x8*)&Bsl[(wn + (nq) * 32 + ni * 16 + l16) * 64  \
                                               + (((kk << 2) + quad) ^ axor) * 8];
#define MMA_Q(mo, no, src)                                                            \
    __builtin_amdgcn_s_setprio(1);                                                    \
    _Pragma("unroll")                                                                 \
    for (int mi = 0; mi < 4; ++mi)                                                    \
        _Pragma("unroll")                                                             \
        for (int ni = 0; ni < 2; ++ni)                                                \
            _Pragma("unroll")                                                         \
            for (int kk = 0; kk < 2; ++kk)                                            \
                acc[(mo) + mi][(no) + ni] = __builtin_amdgcn_mfma_f32_16x16x32_bf16(  \
                    af[mi][kk], src[ni][kk], acc[(mo) + mi][(no) + ni], 0, 0, 0);     \
    __builtin_amdgcn_s_setprio(0);

    const int NK = K >> 6;
    for (int kt = 0; kt < NK - 1; ++kt) {
        const int s = kt & 1;
        const bf16* Asl = smem + s * 32768;
        const bf16* Bsl = Asl + 16384;
        bf16* Asn = smem + (s ^ 1) * 32768;
        bf16* Bsn = Asn + 16384;
        const size_t kn = (size_t)(kt + 1) << 6;
        // pre-stage A of tile kt+1 (slot s^1 was fully read last iteration, behind barriers)
        #pragma unroll
        for (int p = 0; p < 4; ++p)
            GLOBAL_LOAD_LDS16(Abase + (size_t)(p * 8) * K + kn, Asn + (wave * 4 + p) * 512);
        // wait for tile kt's 8 loads (oldest); tile kt+1's 4 A-loads stay in flight
        asm volatile("s_waitcnt vmcnt(4)" ::: "memory");
        BARRIER();
        // ---- ph1: quadrant (0,0); stage B half 0 of tile kt+1
        LOAD_A(0); LOAD_B(0, b0);
        GLOBAL_LOAD_LDS16(Bbase + kn, Bsn + (wave * 4 + 0) * 512);
        GLOBAL_LOAD_LDS16(Bbase + (size_t)8 * K + kn, Bsn + (wave * 4 + 1) * 512);
        MMA_Q(0, 0, b0);
        BARRIER();
        // ---- ph2: quadrant (0,1); stage B half 1 of tile kt+1
        LOAD_B(1, b1);
        GLOBAL_LOAD_LDS16(Bbase + (size_t)16 * K + kn, Bsn + (wave * 4 + 2) * 512);
        GLOBAL_LOAD_LDS16(Bbase + (size_t)24 * K + kn, Bsn + (wave * 4 + 3) * 512);
        MMA_Q(0, 2, b1);
        BARRIER();
        // ---- ph3: quadrant (1,0) — last ds_reads of slot s
        LOAD_A(1);
        MMA_Q(4, 0, b0);
        BARRIER();   // all waves done reading slot s -> next iteration may overwrite it
        // ---- ph4: quadrant (1,1), register-only
        MMA_Q(4, 2, b1);
    }
    {   // peeled last K-tile: drain everything, no staging
        const bf16* Asl = smem + ((NK - 1) & 1) * 32768;
        const bf16* Bsl = Asl + 16384;
        asm volatile("s_waitcnt vmcnt(0)" ::: "memory");
        BARRIER();
        LOAD_A(0); LOAD_B(0, b0);
        MMA_Q(0, 0, b0);
        BARRIER();
        LOAD_B(1, b1);
        MMA_Q(0, 2, b1);
        BARRIER();
        LOAD_A(1);
        MMA_Q(4, 0, b0);
        BARRIER();
        MMA_Q(4, 2, b1);
    }
#undef BARRIER
#undef LOAD_A
#undef LOAD_B
#undef MMA_Q

    const int oddl = l16 & 1;
    if (act) {
        // ---------------- scattered paired-dword epilogue (r6/r15-measured faster for FFN1)
        #pragma unroll
        for (int ni = 0; ni < 4; ++ni) {
            int col = n0 + wn + ni * 16 + l16;
            float bv = bias[col];
            #pragma unroll
            for (int mi = 0; mi < 8; ++mi) {
                float v0 = gelu_f(acc[mi][ni][0] + bv);
                float v1 = gelu_f(acc[mi][ni][1] + bv);
                float v2 = gelu_f(acc[mi][ni][2] + bv);
                float v3 = gelu_f(acc[mi][ni][3] + bv);
                float p0 = __shfl_xor(v0, 1);
                float p1 = __shfl_xor(v1, 1);
                float p2 = __shfl_xor(v2, 1);
                float p3 = __shfl_xor(v3, 1);
                float lo0 = oddl ? p1 : v0, hi0 = oddl ? v1 : p0;
                float lo1 = oddl ? p3 : v2, hi1 = oddl ? v3 : p2;
                int r0 = oddl ? 1 : 0;
                size_t rowb = (size_t)(m0 + wm + mi * 16 + quad * 4);
                unsigned* c0p = (unsigned*)(C + (rowb + r0) * N + (col & ~1));
                unsigned* c1p = (unsigned*)(C + (rowb + r0 + 2) * N + (col & ~1));
                *c0p = pack_bf16(lo0, hi0);
                *c1p = pack_bf16(lo1, hi1);
            }
        }
    } else {
        // ---------------- LDS-staged coalesced epilogue (r7/r15-measured faster for act=0)
        char* ctile = (char*)smem;
        #pragma unroll
        for (int ni = 0; ni < 4; ++ni) {
            int colt = wn + ni * 16 + l16;          // tile col 0..255
            float bv = bias[n0 + colt];
            #pragma unroll
            for (int mi = 0; mi < 8; ++mi) {
                float v0 = acc[mi][ni][0] + bv;
                float v1 = acc[mi][ni][1] + bv;
                float v2 = acc[mi][ni][2] + bv;
                float v3 = acc[mi][ni][3] + bv;
                float p0 = __shfl_xor(v0, 1);
                float p1 = __shfl_xor(v1, 1);
                float p2 = __shfl_xor(v2, 1);
                float p3 = __shfl_xor(v3, 1);
                float lo0 = oddl ? p1 : v0, hi0 = oddl ? v1 : p0;
                float lo1 = oddl ? p3 : v2, hi1 = oddl ? v3 : p2;
                int rowt0 = wm + mi * 16 + quad * 4 + oddl;   // rows +0/+1
                int rowt1 = rowt0 + 2;                        // rows +2/+3
                int colp = colt & ~1;
                *(unsigned*)(ctile + rowt0 * 512 + ((((colp >> 3) ^ (rowt0 & 31)) << 4) | ((colp & 7) << 1)))
                    = pack_bf16(lo0, hi0);
                *(unsigned*)(ctile + rowt1 * 512 + ((((colp >> 3) ^ (rowt1 & 31)) << 4) | ((colp & 7) << 1)))
                    = pack_bf16(lo1, hi1);
            }
        }
        __syncthreads();
        const int rsub = t >> 5;    // 0..15
        const int cch = t & 31;     // 16B chunk 0..31
        #pragma unroll
        for (int g = 0; g < 16; ++g) {
            int row = g * 16 + rsub;
            bf16x8 v = *(const bf16x8*)(ctile + row * 512 + ((cch ^ (row & 31)) << 4));
            *(bf16x8*)(C + (size_t)(m0 + row) * N + n0 + cch * 8) = v;
        }
    }
}

// ---------------------------------------------------------------- MFMA segment attention body (qkv fused input, stride 1536)
template<int LEN>
static __device__ __forceinline__ void attn_body(int bidl,
                                                 const bf16* __restrict__ qkv,
                                                 const bf16* __restrict__ vt,
                                                 bf16* __restrict__ o,
                                                 bf16* __restrict__ Plds) {
    constexpr int NT = LEN / 16;
    constexpr int KT = (LEN >= 32) ? (LEN / 32) : 1;
    constexpr int PST = (LEN == 16) ? 40 : (LEN + 8);
    constexpr int SLABS = LEN / 16;
    constexpr int OFF = LEN - 16;

    const int t = threadIdx.x;
    const int wave = t >> 6, lane = t & 63;
    const int quad = lane >> 4, l16 = lane & 15;
    const int task = bidl * 4 + wave;
    const int b = task / (8 * SLABS);
    const int rem = task - b * (8 * SLABS);
    const int h = rem / SLABS;
    const int slab = rem - h * SLABS;

    const size_t qbase = ((size_t)b * 240 + OFF) * 1536 + h * 64;
    const size_t obase = ((size_t)b * 240 + OFF) * 512 + h * 64;

    const bf16* qp = qkv + qbase + (size_t)(slab * 16 + l16) * 1536 + quad * 8;
    bf16x8 qf0 = *(const bf16x8*)qp;
    bf16x8 qf1 = *(const bf16x8*)(qp + 32);

    f32x4 sacc[NT];
    #pragma unroll
    for (int nt = 0; nt < NT; ++nt) {
        const bf16* kp = qkv + qbase + 512 + (size_t)(nt * 16 + l16) * 1536 + quad * 8;
        bf16x8 kf0 = *(const bf16x8*)kp;
        bf16x8 kf1 = *(const bf16x8*)(kp + 32);
        f32x4 a = {0.f, 0.f, 0.f, 0.f};
        a = __builtin_amdgcn_mfma_f32_16x16x32_bf16(qf0, kf0, a, 0, 0, 0);
        a = __builtin_amdgcn_mfma_f32_16x16x32_bf16(qf1, kf1, a, 0, 0, 0);
        sacc[nt] = a;
    }

    float mx[4], sm[4];
    #pragma unroll
    for (int r = 0; r < 4; ++r) mx[r] = -3.0e38f;
    #pragma unroll
    for (int nt = 0; nt < NT; ++nt)
        #pragma unroll
        for (int r = 0; r < 4; ++r) {
            sacc[nt][r] *= 0.125f;
            mx[r] = fmaxf(mx[r], sacc[nt][r]);
        }
    #pragma unroll
    for (int msk = 1; msk < 16; msk <<= 1)
        #pragma unroll
        for (int r = 0; r < 4; ++r) mx[r] = fmaxf(mx[r], __shfl_xor(mx[r], msk));
    #pragma unroll
    for (int r = 0; r < 4; ++r) sm[r] = 0.f;
    #pragma unroll
    for (int nt = 0; nt < NT; ++nt)
        #pragma unroll
        for (int r = 0; r < 4; ++r) {
            float p = __expf(sacc[nt][r] - mx[r]);
            sacc[nt][r] = p;
            sm[r] += p;
        }
    #pragma unroll
    for (int msk = 1; msk < 16; msk <<= 1)
        #pragma unroll
        for (int r = 0; r < 4; ++r) sm[r] += __shfl_xor(sm[r], msk);
    float inv[4];
    #pragma unroll
    for (int r = 0; r < 4; ++r) inv[r] = 1.f / sm[r];

    bf16* pw = Plds + wave * 16 * PST;
    #pragma unroll
    for (int nt = 0; nt < NT; ++nt)
        #pragma unroll
        for (int r = 0; r < 4; ++r)
            pw[(quad * 4 + r) * PST + nt * 16 + l16] =
                __float2bfloat16(sacc[nt][r] * inv[r]);
    if (LEN == 16) {
        #pragma unroll
        for (int r = 0; r < 4; ++r)
            pw[(quad * 4 + r) * PST + 16 + l16] = __float2bfloat16(0.f);
    }
    __syncthreads();

    f32x4 oacc[4];
    #pragma unroll
    for (int n4 = 0; n4 < 4; ++n4) {
        f32x4 z = {0.f, 0.f, 0.f, 0.f};
        oacc[n4] = z;
    }
    #pragma unroll
    for (int kt = 0; kt < KT; ++kt) {
        bf16x8 pf = *(const bf16x8*)&pw[l16 * PST + kt * 32 + quad * 8];
        #pragma unroll
        for (int n4 = 0; n4 < 4; ++n4) {
            const bf16* vp = vt + ((size_t)b * 512 + h * 64 + n4 * 16 + l16) * 240
                              + OFF + kt * 32 + quad * 8;
            bf16x8 vf = *(const bf16x8*)vp;
            oacc[n4] = __builtin_amdgcn_mfma_f32_16x16x32_bf16(pf, vf, oacc[n4], 0, 0, 0);
        }
    }
    #pragma unroll
    for (int n4 = 0; n4 < 4; ++n4)
        #pragma unroll
        for (int r = 0; r < 4; ++r)
            o[obase + (size_t)(slab * 16 + quad * 4 + r) * 512 + n4 * 16 + l16] =
                __float2bfloat16(oacc[n4][r]);
}

// merged dispatcher: blocks [0,512) LEN=16, [512,1536) LEN=32, [1536,3584) LEN=64, [3584,7680) LEN=128
__global__ __launch_bounds__(256) void attn_all(const bf16* __restrict__ qkv,
                                                const bf16* __restrict__ vt,
                                                bf16* __restrict__ o) {
    __shared__ __align__(16) bf16 Plds[4 * 16 * 136];   // sized for LEN=128 (PST=136)
    int bid = blockIdx.x;
    if (bid < 512)        attn_body<16>(bid, qkv, vt, o, Plds);
    else if (bid < 1536)  attn_body<32>(bid - 512, qkv, vt, o, Plds);
    else if (bid < 3584)  attn_body<64>(bid - 1536, qkv, vt, o, Plds);
    else                  attn_body<128>(bid - 3584, qkv, vt, o, Plds);
}

// ---------------------------------------------------------------- residual + layernorm (row = 512)
// one row per WAVE: 64 lanes x bf16x8 = 512 elems; pure shfl reduce, no LDS (G13 vectorized)
__global__ __launch_bounds__(256) void ln_kernel(const bf16* x, const bf16* res,
                                                 const float* __restrict__ g,
                                                 const float* __restrict__ bta,
                                                 bf16* out_bf, float* out_f) {
    const int wave = threadIdx.x >> 6, lane = threadIdx.x & 63;
    const int row = blockIdx.x * 4 + wave;
    const size_t base = (size_t)row * 512 + lane * 8;

    bf16x8 xv = *(const bf16x8*)(x + base);
    const bf16* xe = (const bf16*)&xv;
    float v[8];
    #pragma unroll
    for (int i = 0; i < 8; ++i) v[i] = __bfloat162float(xe[i]);
    if (res) {
        bf16x8 rv = *(const bf16x8*)(res + base);
        const bf16* re = (const bf16*)&rv;
        #pragma unroll
        for (int i = 0; i < 8; ++i) v[i] += __bfloat162float(re[i]);
    }
    float s = 0.f, ss = 0.f;
    #pragma unroll
    for (int i = 0; i < 8; ++i) { s += v[i]; ss += v[i] * v[i]; }
    #pragma unroll
    for (int mk = 1; mk < 64; mk <<= 1) { s += __shfl_xor(s, mk); ss += __shfl_xor(ss, mk); }
    float mu = s * (1.f / 512.f);
    float var = ss * (1.f / 512.f) - mu * mu;
    float inv = rsqrtf(var + 1e-5f);

    f32x4 g0 = *(const f32x4*)(g + lane * 8);
    f32x4 g1 = *(const f32x4*)(g + lane * 8 + 4);
    f32x4 b0 = *(const f32x4*)(bta + lane * 8);
    f32x4 b1 = *(const f32x4*)(bta + lane * 8 + 4);
    float y[8];
    #pragma unroll
    for (int i = 0; i < 4; ++i) y[i] = (v[i] - mu) * inv * g0[i] + b0[i];
    #pragma unroll
    for (int i = 0; i < 4; ++i) y[i + 4] = (v[i + 4] - mu) * inv * g1[i] + b1[i];

    if (out_bf) {
        bf16x8 ov;
        bf16* oe = (bf16*)&ov;
        #pragma unroll
        for (int i = 0; i < 8; ++i) oe[i] = __float2bfloat16(y[i]);
        *(bf16x8*)(out_bf + base) = ov;
    } else {
        f32x4 o0 = {y[0], y[1], y[2], y[3]};
        f32x4 o1 = {y[4], y[5], y[6], y[7]};
        *(f32x4*)(out_f + base) = o0;
        *(f32x4*)(out_f + base + 4) = o1;
    }
}

// ---------------------------------------------------------------- launch
extern "C" void kernel_launch(void* const* d_in, const int* in_sizes, int n_in,
                              void* d_out, int out_size, void* d_ws, size_t ws_size,
                              hipStream_t stream) {
    const float* x_enc = (const float*)d_in[0];
    const float* W_emb = (const float*)d_in[1];
    const float* Wq    = (const float*)d_in[2];
    const float* bq    = (const float*)d_in[3];
    const float* Wk    = (const float*)d_in[4];
    const float* bk    = (const float*)d_in[5];
    const float* Wv    = (const float*)d_in[6];
    const float* bv    = (const float*)d_in[7];
    const float* Wo    = (const float*)d_in[8];
    const float* bo    = (const float*)d_in[9];
    const float* ln1_g = (const float*)d_in[10];
    const float* ln1_b = (const float*)d_in[11];
    const float* W1    = (const float*)d_in[12];
    const float* b1    = (const float*)d_in[13];
    const float* W2    = (const float*)d_in[14];
    const float* b2    = (const float*)d_in[15];
    const float* ln2_g = (const float*)d_in[16];
    const float* ln2_b = (const float*)d_in[17];
    const float* lnf_g = (const float*)d_in[18];
    const float* lnf_b = (const float*)d_in[19];

    const int ROWS = 256 * 240;            // 61440
    char* ws = (char*)d_ws;
    const size_t Hb = (size_t)ROWS * 512 * 2;  // 62,914,560 B
    bf16* h    = (bf16*)(ws);
    bf16* qkv  = (bf16*)(ws + Hb);         // [ROWS][1536]; q|k|v
    bf16* oa   = (bf16*)(ws + 4 * Hb);     // attention output [ROWS][512]
    bf16* scr2 = (bf16*)(ws + 5 * Hb);     // vt during attn; oproj; ffnout
    bf16* mid  = qkv;                      // FFN mid [ROWS][2048] aliases qkv+oa (4*Hb)
    bf16* WqkvT = (bf16*)(ws + 6 * Hb);    // [L][1536][512]
    bf16* WoT  = WqkvT + (size_t)3 * 1536 * 512;
    bf16* W1T  = WoT + (size_t)3 * 512 * 512;
    bf16* W2T  = W1T + (size_t)3 * 512 * 2048;
    float* bcat = (float*)(W2T + (size_t)3 * 2048 * 512);   // [L][1536]
    float* petab = bcat + 3 * 1536;                          // [240][512]

    bf16* vt     = scr2;
    bf16* oproj  = scr2;
    bf16* ffnout = scr2;

    dim3 blk(256);
    dim3 gblk(512);
    transpose_f32_bf16<<<dim3(16, 16, 3), blk, 0, stream>>>(Wq, WqkvT, 512, 512, (size_t)1536 * 512);
    transpose_f32_bf16<<<dim3(16, 16, 3), blk, 0, stream>>>(Wk, WqkvT + (size_t)512 * 512, 512, 512, (size_t)1536 * 512);
    transpose_f32_bf16<<<dim3(16, 16, 3), blk, 0, stream>>>(Wv, WqkvT + (size_t)1024 * 512, 512, 512, (size_t)1536 * 512);
    transpose_f32_bf16<<<dim3(16, 16, 3), blk, 0, stream>>>(Wo, WoT, 512, 512, (size_t)512 * 512);
    transpose_f32_bf16<<<dim3(64, 16, 3), blk, 0, stream>>>(W1, W1T, 512, 2048, (size_t)512 * 2048);
    transpose_f32_bf16<<<dim3(16, 64, 3), blk, 0, stream>>>(W2, W2T, 2048, 512, (size_t)2048 * 512);
    concat_bias<<<18, blk, 0, stream>>>(bq, bk, bv, bcat);
    pe_table<<<240, blk, 0, stream>>>(petab);

    embed_kernel<<<ROWS, blk, 0, stream>>>(x_enc, W_emb, petab, h);

    for (int L = 0; L < 3; ++L) {
        size_t wo = (size_t)L * 512 * 512;
        size_t w1o = (size_t)L * 512 * 2048;
        gemm_bt_256<<<dim3(6, 240), gblk, 0, stream>>>(h, WqkvT + (size_t)L * 1536 * 512,
                                                       bcat + L * 1536, qkv, ROWS, 1536, 512, 0);
        transpose_v<<<dim3(16, 8, 256), blk, 0, stream>>>(qkv, vt);
        attn_all<<<7680, blk, 0, stream>>>(qkv, vt, oa);
        gemm_bt_256<<<dim3(2, 240), gblk, 0, stream>>>(oa, WoT + wo, bo + L * 512, oproj, ROWS, 512, 512, 0);
        ln_kernel<<<ROWS / 4, blk, 0, stream>>>(h, oproj, ln1_g + L * 512, ln1_b + L * 512, h, nullptr);
        gemm_bt_256<<<dim3(8, 240), gblk, 0, stream>>>(h, W1T + w1o, b1 + L * 2048, mid, ROWS, 2048, 512, 1);
        gemm_bt_256<<<dim3(2, 240), gblk, 0, stream>>>(mid, W2T + w1o, b2 + L * 512, ffnout, ROWS, 512, 2048, 0);
        ln_kernel<<<ROWS / 4, blk, 0, stream>>>(h, ffnout, ln2_g + L * 512, ln2_b + L * 512, h, nullptr);
    }
    ln_kernel<<<ROWS / 4, blk, 0, stream>>>(h, nullptr, lnf_g, lnf_b, nullptr, (float*)d_out);
}